// Round 2
// baseline (954.956 us; speedup 1.0000x reference)
//
#include <hip/hip_runtime.h>

#define NN 100000
#define DD 384
#define CC 8

__device__ __forceinline__ constexpr int TIDX(int i, int j) { return i * (i + 1) / 2 + j; }

// Pack per-channel record: [0..35] lower-tri (i>=j) of Sigmaw[d] + wbar[d] wbar[d]^T,
// [36..43] wbar[d][0..7], [44] mbar[d], [45..47] pad.  48 floats per d, 16B aligned.
__global__ __launch_bounds__(64) void vbpca_prep(
    const float* __restrict__ mbar, const float* __restrict__ wbar,
    const float* __restrict__ Sigmaw, float* __restrict__ rec) {
  int d = blockIdx.x * 64 + threadIdx.x;
  if (d >= DD) return;
  float w[CC];
#pragma unroll
  for (int i = 0; i < CC; ++i) w[i] = wbar[d * CC + i];
  float* r = rec + d * 48;
#pragma unroll
  for (int i = 0; i < CC; ++i) {
#pragma unroll
    for (int j = 0; j <= i; ++j) {
      r[TIDX(i, j)] = Sigmaw[(size_t)d * 64 + i * 8 + j] + w[i] * w[j];
    }
  }
#pragma unroll
  for (int i = 0; i < CC; ++i) r[36 + i] = w[i];
  r[44] = mbar[d];
  r[45] = 0.f; r[46] = 0.f; r[47] = 0.f;
}

// 256 threads = 4 waves per block; block owns 64 rows; wave w accumulates
// channels [w*96, w*96+96); partials reduced via LDS; wave 0 solves+stores.
__global__ __launch_bounds__(256, 4) void vbpca_main(
    const float* __restrict__ Y, const int* __restrict__ O,
    const float* __restrict__ rec, const float* __restrict__ vyp,
    float* __restrict__ out) {
  const int wave = threadIdx.x >> 6;
  const int lane = threadIdx.x & 63;
  const int row = blockIdx.x * 64 + lane;
  const int rowc = (row < NN) ? row : (NN - 1);  // clamp loads, guard stores

  __shared__ float part[3][44][64];  // 33792 B

  const float4* __restrict__ Y4 = reinterpret_cast<const float4*>(Y) + (size_t)rowc * (DD / 4);
  const int4* __restrict__ O4 = reinterpret_cast<const int4*>(O) + (size_t)rowc * (DD / 4);

  float a[36];
  float pr[CC];
#pragma unroll
  for (int k = 0; k < 36; ++k) a[k] = 0.f;
#pragma unroll
  for (int j = 0; j < CC; ++j) pr[j] = 0.f;

  const int c0 = wave * (DD / 4 / 4);  // 24 float4-groups per wave
  for (int c = c0; c < c0 + (DD / 4 / 4); ++c) {
    const float4 y4 = Y4[c];
    const int4 o4 = O4[c];
    const float4* __restrict__ r4 = reinterpret_cast<const float4*>(rec) + (size_t)c * 48;
#pragma unroll
    for (int u = 0; u < 4; ++u) {
      float rv[48];
#pragma unroll
      for (int q = 0; q < 12; ++q) {
        const float4 t4 = r4[u * 12 + q];
        rv[q * 4 + 0] = t4.x; rv[q * 4 + 1] = t4.y;
        rv[q * 4 + 2] = t4.z; rv[q * 4 + 3] = t4.w;
      }
      const float yv = (u == 0) ? y4.x : (u == 1) ? y4.y : (u == 2) ? y4.z : y4.w;
      const int oi = (u == 0) ? o4.x : (u == 1) ? o4.y : (u == 2) ? o4.z : o4.w;
      const float of = (float)oi;          // mask is 0/1
      const float tv = of * (yv - rv[44]); // O * (Y - mbar)
#pragma unroll
      for (int k = 0; k < 36; ++k) a[k] = fmaf(of, rv[k], a[k]);
#pragma unroll
      for (int j = 0; j < CC; ++j) pr[j] = fmaf(tv, rv[36 + j], pr[j]);
    }
  }

  // ---- cross-wave reduction via LDS (lane-major: conflict-free) ----
  if (wave != 0) {
#pragma unroll
    for (int k = 0; k < 36; ++k) part[wave - 1][k][lane] = a[k];
#pragma unroll
    for (int j = 0; j < CC; ++j) part[wave - 1][36 + j][lane] = pr[j];
  }
  __syncthreads();
  if (wave != 0) return;

#pragma unroll
  for (int w = 0; w < 3; ++w) {
#pragma unroll
    for (int k = 0; k < 36; ++k) a[k] += part[w][k][lane];
#pragma unroll
    for (int j = 0; j < CC; ++j) pr[j] += part[w][36 + j][lane];
  }

  const float vy = *vyp;

  // ---- Solve: M = vy*I + A (SPD, packed lower-tri in a[] + vy on diag) ----
  float L[36];
#pragma unroll
  for (int j = 0; j < CC; ++j) {
    float s = a[TIDX(j, j)] + vy;
#pragma unroll
    for (int k = 0; k < CC; ++k) {
      if (k < j) s -= L[TIDX(j, k)] * L[TIDX(j, k)];
    }
    const float dj = sqrtf(s);
    L[TIDX(j, j)] = dj;
    const float invdj = 1.0f / dj;
#pragma unroll
    for (int i = j + 1; i < CC; ++i) {
      float t = a[TIDX(i, j)];
#pragma unroll
      for (int k = 0; k < CC; ++k) {
        if (k < j) t -= L[TIDX(i, k)] * L[TIDX(j, k)];
      }
      L[TIDX(i, j)] = t * invdj;
    }
  }

  // Li = L^{-1} (lower triangular)
  float invd[CC];
#pragma unroll
  for (int i = 0; i < CC; ++i) invd[i] = 1.0f / L[TIDX(i, i)];
  float Li[36];
#pragma unroll
  for (int j = 0; j < CC; ++j) {
    Li[TIDX(j, j)] = invd[j];
#pragma unroll
    for (int i = j + 1; i < CC; ++i) {
      float s = 0.f;
#pragma unroll
      for (int k = 0; k < CC; ++k) {
        if (k >= j && k < i) s += L[TIDX(i, k)] * Li[TIDX(k, j)];
      }
      Li[TIDX(i, j)] = -s * invd[i];
    }
  }

  // Sigma = vy * Li^T Li (packed lower-tri, i>=j): sum_{k>=i} Li[k][i]*Li[k][j]
  float sig[36];
#pragma unroll
  for (int i = 0; i < CC; ++i) {
#pragma unroll
    for (int j = 0; j <= i; ++j) {
      float s = 0.f;
#pragma unroll
      for (int k = 0; k < CC; ++k) {
        if (k >= i) s += Li[TIDX(k, i)] * Li[TIDX(k, j)];
      }
      sig[TIDX(i, j)] = vy * s;
    }
  }

  // xbar = M^{-1} proj = Li^T (Li proj)
  float uvec[CC];
#pragma unroll
  for (int i = 0; i < CC; ++i) {
    float s = 0.f;
#pragma unroll
    for (int j = 0; j < CC; ++j) {
      if (j <= i) s += Li[TIDX(i, j)] * pr[j];
    }
    uvec[i] = s;
  }
  float xb[CC];
#pragma unroll
  for (int l = 0; l < CC; ++l) {
    float s = 0.f;
#pragma unroll
    for (int i = 0; i < CC; ++i) {
      if (i >= l) s += Li[TIDX(i, l)] * uvec[i];
    }
    xb[l] = s;
  }

  if (row >= NN) return;

  // ---- Write outputs: xbarn [N,8] then Sigma_xn [N,8,8] ----
  float4* __restrict__ xo = reinterpret_cast<float4*>(out + (size_t)row * CC);
  xo[0] = make_float4(xb[0], xb[1], xb[2], xb[3]);
  xo[1] = make_float4(xb[4], xb[5], xb[6], xb[7]);

  float4* __restrict__ so4 =
      reinterpret_cast<float4*>(out + (size_t)NN * CC + (size_t)row * 64);
#pragma unroll
  for (int i = 0; i < CC; ++i) {
    float rowv[CC];
#pragma unroll
    for (int j = 0; j < CC; ++j) {
      rowv[j] = (j <= i) ? sig[TIDX(i, j)] : sig[TIDX(j, i)];
    }
    so4[i * 2 + 0] = make_float4(rowv[0], rowv[1], rowv[2], rowv[3]);
    so4[i * 2 + 1] = make_float4(rowv[4], rowv[5], rowv[6], rowv[7]);
  }
}

extern "C" void kernel_launch(void* const* d_in, const int* in_sizes, int n_in,
                              void* d_out, int out_size, void* d_ws, size_t ws_size,
                              hipStream_t stream) {
  const float* Y = (const float*)d_in[0];
  const int* O = (const int*)d_in[1];
  const float* mbar = (const float*)d_in[2];
  const float* wbar = (const float*)d_in[3];
  const float* Sigmaw = (const float*)d_in[4];
  const float* vyp = (const float*)d_in[5];
  float* out = (float*)d_out;
  float* rec = (float*)d_ws;  // 384*48*4 = 73728 bytes

  vbpca_prep<<<(DD + 63) / 64, 64, 0, stream>>>(mbar, wbar, Sigmaw, rec);
  vbpca_main<<<(NN + 63) / 64, 256, 0, stream>>>(Y, O, rec, vyp, out);
}

// Round 3
// 326.784 us; speedup vs baseline: 2.9223x; 2.9223x over previous
//
#include <hip/hip_runtime.h>

#define NN 100000
#define DD 384
#define CC 8

__device__ __forceinline__ constexpr int TIDX(int i, int j) { return i * (i + 1) / 2 + j; }

// Record per channel d (48 floats, 16B aligned):
// [0]=mbar, [1..8]=wbar[0..7], [9..44]=lower-tri (i>=j) of Sigmaw[d]+wbar wbar^T, [45..47]=0
__global__ __launch_bounds__(64) void vbpca_prep(
    const float* __restrict__ mbar, const float* __restrict__ wbar,
    const float* __restrict__ Sigmaw, float* __restrict__ rec) {
  int d = blockIdx.x * 64 + threadIdx.x;
  if (d >= DD) return;
  float w[CC];
#pragma unroll
  for (int i = 0; i < CC; ++i) w[i] = wbar[d * CC + i];
  float* r = rec + d * 48;
  r[0] = mbar[d];
#pragma unroll
  for (int i = 0; i < CC; ++i) r[1 + i] = w[i];
#pragma unroll
  for (int i = 0; i < CC; ++i) {
#pragma unroll
    for (int j = 0; j <= i; ++j) {
      r[9 + TIDX(i, j)] = Sigmaw[(size_t)d * 64 + i * 8 + j] + w[i] * w[j];
    }
  }
  r[45] = 0.f; r[46] = 0.f; r[47] = 0.f;
}

// 256 threads = 4 waves; block owns 64 rows; wave w accumulates channels
// [w*96, w*96+96); partials reduced via LDS; wave 0 solves + stores.
// Records consumed float4-at-a-time (no staging array -> no spills); record
// addresses made provably wave-uniform via readfirstlane -> s_load stream.
__global__ __launch_bounds__(256, 4) void vbpca_main(
    const float* __restrict__ Y, const int* __restrict__ O,
    const float* __restrict__ rec, const float* __restrict__ vyp,
    float* __restrict__ out) {
  const int wavei = __builtin_amdgcn_readfirstlane((int)(threadIdx.x >> 6));
  const int lane = threadIdx.x & 63;
  const int row = blockIdx.x * 64 + lane;
  const int rowc = (row < NN) ? row : (NN - 1);  // clamp loads, guard stores

  __shared__ float part[3][44][64];  // 33792 B -> 4 blocks/CU

  const float4* __restrict__ Y4 =
      reinterpret_cast<const float4*>(Y) + (size_t)rowc * (DD / 4);
  const int4* __restrict__ O4 =
      reinterpret_cast<const int4*>(O) + (size_t)rowc * (DD / 4);
  const float4* __restrict__ rec4 = reinterpret_cast<const float4*>(rec);

  float a[36];
  float pr[CC];
#pragma unroll
  for (int k = 0; k < 36; ++k) a[k] = 0.f;
#pragma unroll
  for (int j = 0; j < CC; ++j) pr[j] = 0.f;

  const int c0 = wavei * (DD / 4 / 4);  // 24 float4-groups of rows per wave
  for (int c = c0; c < c0 + (DD / 4 / 4); ++c) {
    const float4 y4 = Y4[c];
    const int4 o4 = O4[c];
    const float4* __restrict__ r4 = rec4 + (size_t)c * 48;
#pragma unroll
    for (int u = 0; u < 4; ++u) {
      const float yv = (u == 0) ? y4.x : (u == 1) ? y4.y : (u == 2) ? y4.z : y4.w;
      const int oi = (u == 0) ? o4.x : (u == 1) ? o4.y : (u == 2) ? o4.z : o4.w;
      const float of = (float)oi;  // mask is 0/1

      float4 t = r4[u * 12 + 0];  // mbar, w0, w1, w2
      const float tv = of * (yv - t.x);
      pr[0] = fmaf(tv, t.y, pr[0]);
      pr[1] = fmaf(tv, t.z, pr[1]);
      pr[2] = fmaf(tv, t.w, pr[2]);

      t = r4[u * 12 + 1];  // w3..w6
      pr[3] = fmaf(tv, t.x, pr[3]);
      pr[4] = fmaf(tv, t.y, pr[4]);
      pr[5] = fmaf(tv, t.z, pr[5]);
      pr[6] = fmaf(tv, t.w, pr[6]);

      t = r4[u * 12 + 2];  // w7, tri0, tri1, tri2
      pr[7] = fmaf(tv, t.x, pr[7]);
      a[0] = fmaf(of, t.y, a[0]);
      a[1] = fmaf(of, t.z, a[1]);
      a[2] = fmaf(of, t.w, a[2]);

#pragma unroll
      for (int q = 3; q < 11; ++q) {  // tri[3..34]
        t = r4[u * 12 + q];
        a[4 * q - 9] = fmaf(of, t.x, a[4 * q - 9]);
        a[4 * q - 8] = fmaf(of, t.y, a[4 * q - 8]);
        a[4 * q - 7] = fmaf(of, t.z, a[4 * q - 7]);
        a[4 * q - 6] = fmaf(of, t.w, a[4 * q - 6]);
      }

      t = r4[u * 12 + 11];  // tri35, pad, pad, pad
      a[35] = fmaf(of, t.x, a[35]);
    }
  }

  // ---- cross-wave reduction via LDS (lane-major: conflict-free) ----
  if (wavei != 0) {
#pragma unroll
    for (int k = 0; k < 36; ++k) part[wavei - 1][k][lane] = a[k];
#pragma unroll
    for (int j = 0; j < CC; ++j) part[wavei - 1][36 + j][lane] = pr[j];
  }
  __syncthreads();
  if (wavei != 0) return;

#pragma unroll
  for (int w = 0; w < 3; ++w) {
#pragma unroll
    for (int k = 0; k < 36; ++k) a[k] += part[w][k][lane];
#pragma unroll
    for (int j = 0; j < CC; ++j) pr[j] += part[w][36 + j][lane];
  }

  const float vy = *vyp;

  // ---- Solve: M = vy*I + A (SPD, packed lower-tri in a[] + vy on diag) ----
  float L[36];
#pragma unroll
  for (int j = 0; j < CC; ++j) {
    float s = a[TIDX(j, j)] + vy;
#pragma unroll
    for (int k = 0; k < CC; ++k) {
      if (k < j) s -= L[TIDX(j, k)] * L[TIDX(j, k)];
    }
    const float dj = sqrtf(s);
    L[TIDX(j, j)] = dj;
    const float invdj = 1.0f / dj;
#pragma unroll
    for (int i = j + 1; i < CC; ++i) {
      float tt = a[TIDX(i, j)];
#pragma unroll
      for (int k = 0; k < CC; ++k) {
        if (k < j) tt -= L[TIDX(i, k)] * L[TIDX(j, k)];
      }
      L[TIDX(i, j)] = tt * invdj;
    }
  }

  // Li = L^{-1} (lower triangular)
  float invd[CC];
#pragma unroll
  for (int i = 0; i < CC; ++i) invd[i] = 1.0f / L[TIDX(i, i)];
  float Li[36];
#pragma unroll
  for (int j = 0; j < CC; ++j) {
    Li[TIDX(j, j)] = invd[j];
#pragma unroll
    for (int i = j + 1; i < CC; ++i) {
      float s = 0.f;
#pragma unroll
      for (int k = 0; k < CC; ++k) {
        if (k >= j && k < i) s += L[TIDX(i, k)] * Li[TIDX(k, j)];
      }
      Li[TIDX(i, j)] = -s * invd[i];
    }
  }

  // Sigma = vy * Li^T Li (packed lower-tri, i>=j): sum_{k>=i} Li[k][i]*Li[k][j]
  float sig[36];
#pragma unroll
  for (int i = 0; i < CC; ++i) {
#pragma unroll
    for (int j = 0; j <= i; ++j) {
      float s = 0.f;
#pragma unroll
      for (int k = 0; k < CC; ++k) {
        if (k >= i) s += Li[TIDX(k, i)] * Li[TIDX(k, j)];
      }
      sig[TIDX(i, j)] = vy * s;
    }
  }

  // xbar = M^{-1} proj = Li^T (Li proj)
  float uvec[CC];
#pragma unroll
  for (int i = 0; i < CC; ++i) {
    float s = 0.f;
#pragma unroll
    for (int j = 0; j < CC; ++j) {
      if (j <= i) s += Li[TIDX(i, j)] * pr[j];
    }
    uvec[i] = s;
  }
  float xb[CC];
#pragma unroll
  for (int l = 0; l < CC; ++l) {
    float s = 0.f;
#pragma unroll
    for (int i = 0; i < CC; ++i) {
      if (i >= l) s += Li[TIDX(i, l)] * uvec[i];
    }
    xb[l] = s;
  }

  if (row >= NN) return;

  // ---- Write outputs: xbarn [N,8] then Sigma_xn [N,8,8] ----
  float4* __restrict__ xo = reinterpret_cast<float4*>(out + (size_t)row * CC);
  xo[0] = make_float4(xb[0], xb[1], xb[2], xb[3]);
  xo[1] = make_float4(xb[4], xb[5], xb[6], xb[7]);

  float4* __restrict__ so4 =
      reinterpret_cast<float4*>(out + (size_t)NN * CC + (size_t)row * 64);
#pragma unroll
  for (int i = 0; i < CC; ++i) {
    float rowv[CC];
#pragma unroll
    for (int j = 0; j < CC; ++j) {
      rowv[j] = (j <= i) ? sig[TIDX(i, j)] : sig[TIDX(j, i)];
    }
    so4[i * 2 + 0] = make_float4(rowv[0], rowv[1], rowv[2], rowv[3]);
    so4[i * 2 + 1] = make_float4(rowv[4], rowv[5], rowv[6], rowv[7]);
  }
}

extern "C" void kernel_launch(void* const* d_in, const int* in_sizes, int n_in,
                              void* d_out, int out_size, void* d_ws, size_t ws_size,
                              hipStream_t stream) {
  const float* Y = (const float*)d_in[0];
  const int* O = (const int*)d_in[1];
  const float* mbar = (const float*)d_in[2];
  const float* wbar = (const float*)d_in[3];
  const float* Sigmaw = (const float*)d_in[4];
  const float* vyp = (const float*)d_in[5];
  float* out = (float*)d_out;
  float* rec = (float*)d_ws;  // 384*48*4 = 73728 bytes

  vbpca_prep<<<(DD + 63) / 64, 64, 0, stream>>>(mbar, wbar, Sigmaw, rec);
  vbpca_main<<<(NN + 63) / 64, 256, 0, stream>>>(Y, O, rec, vyp, out);
}

// Round 5
// 118.478 us; speedup vs baseline: 8.0602x; 2.7582x over previous
//
#include <hip/hip_runtime.h>

#define NN 100000
#define DD 384
#define CC 8

typedef unsigned int uint;
typedef _Float16 half2v __attribute__((ext_vector_type(2)));

__device__ __forceinline__ constexpr int TIDX(int i, int j) { return i * (i + 1) / 2 + j; }

__device__ __forceinline__ uint pkh2(float a, float b) {
  return __builtin_bit_cast(uint, __builtin_amdgcn_cvt_pkrtz(a, b));
}

__device__ __forceinline__ float dot2(uint a, uint b, float c) {
#if __has_builtin(__builtin_amdgcn_fdot2)
  return __builtin_amdgcn_fdot2(__builtin_bit_cast(half2v, a),
                                __builtin_bit_cast(half2v, b), c, false);
#else
  half2v ha = __builtin_bit_cast(half2v, a), hb = __builtin_bit_cast(half2v, b);
  return c + (float)ha.x * (float)hb.x + (float)ha.y * (float)hb.y;
#endif
}

// Pack channel-PAIR records as f16x2: pair p covers channels d0=2p, d1=2p+1.
// recpk[p][k] k<36: pack(tri_{d0}[k], tri_{d1}[k]); k=36..43: pack(w_{d0}[k-36], w_{d1}[k-36]).
__global__ __launch_bounds__(64) void vbpca_prep(
    const float* __restrict__ wbar, const float* __restrict__ Sigmaw,
    uint* __restrict__ recpk) {
  int p = blockIdx.x * 64 + threadIdx.x;
  if (p >= DD / 2) return;
  const int d0 = 2 * p, d1 = 2 * p + 1;
  float w0[CC], w1[CC];
#pragma unroll
  for (int i = 0; i < CC; ++i) {
    w0[i] = wbar[d0 * CC + i];
    w1[i] = wbar[d1 * CC + i];
  }
  uint* r = recpk + (size_t)p * 44;
#pragma unroll
  for (int i = 0; i < CC; ++i) {
#pragma unroll
    for (int j = 0; j <= i; ++j) {
      float t0 = Sigmaw[(size_t)d0 * 64 + i * 8 + j] + w0[i] * w0[j];
      float t1 = Sigmaw[(size_t)d1 * 64 + i * 8 + j] + w1[i] * w1[j];
      r[TIDX(i, j)] = pkh2(t0, t1);
    }
  }
#pragma unroll
  for (int j = 0; j < CC; ++j) r[36 + j] = pkh2(w0[j], w1[j]);
}

#define ROWS 128
#define NCHUNK 12

// 256 threads = 4 waves. Group g = tid>>7 (2 waves) handles channels
// [g*192, g*192+192) for rows [blk*128, blk*128+128). Thread r=tid&127 owns row r.
// Per chunk (16 ch per group): coalesced global load -> f16-pair pack -> LDS
// transpose -> dot2 accumulate vs LDS-broadcast records. Part-reduce, solve.
__global__ __launch_bounds__(256, 3) void vbpca_main(
    const float* __restrict__ Y, const int* __restrict__ O,
    const uint* __restrict__ recpk, const float* __restrict__ mbar,
    const float* __restrict__ vyp, float* __restrict__ out) {
  __shared__ uint4 smem[3360];  // 53760 B
  uint* rec_l = (uint*)smem;               // [192][44] u32 (f16x2)  = 33792 B
  float* mbar_l = (float*)(rec_l + 8448);  // [384]                  = 1536 B
  uint* tile_l = (uint*)(mbar_l + 384);    // [2][128][18] u32       = 18432 B
  float* part_l = (float*)smem;            // [44][128] overlay on rec region

  const int tid = threadIdx.x;
  const int g = tid >> 7;
  const int r = tid & 127;
  const int grow = blockIdx.x * ROWS + r;

  // Stage records + mbar into LDS.
  for (int i = tid; i < 2112; i += 256) smem[i] = ((const uint4*)recpk)[i];
  for (int i = tid; i < 384; i += 256) mbar_l[i] = mbar[i];

  float4 yv[4];
  int4 ov[4];
#define ISSUE_LOADS(IT)                                                        \
  {                                                                            \
    _Pragma("unroll") for (int q = 0; q < 4; ++q) {                            \
      const int f = q * 256 + tid;                                             \
      const int gp = f >> 9, fr = f & 511;                                     \
      const int row = fr >> 2, c4 = fr & 3;                                    \
      int rg = blockIdx.x * ROWS + row;                                        \
      rg = rg < NN ? rg : NN - 1;                                              \
      const int ch = gp * 192 + (IT)*16 + c4 * 4;                              \
      yv[q] = *reinterpret_cast<const float4*>(Y + (size_t)rg * DD + ch);      \
      ov[q] = *reinterpret_cast<const int4*>(O + (size_t)rg * DD + ch);        \
    }                                                                          \
  }

  ISSUE_LOADS(0);
  __syncthreads();  // records + mbar ready

  float a[36];
  float pr[CC];
#pragma unroll
  for (int k = 0; k < 36; ++k) a[k] = 0.f;
#pragma unroll
  for (int j = 0; j < CC; ++j) pr[j] = 0.f;

  for (int it = 0; it < NCHUNK; ++it) {
    if (it) __syncthreads();  // previous chunk's tile reads complete

    // Convert + transpose into LDS tile.
#pragma unroll
    for (int q = 0; q < 4; ++q) {
      const int f = q * 256 + tid;
      const int gp = f >> 9, fr = f & 511;
      const int row = fr >> 2, c4 = fr & 3;
      const int ch = gp * 192 + it * 16 + c4 * 4;
      const float4 mb = *reinterpret_cast<const float4*>(mbar_l + ch);
      const float o0 = (float)ov[q].x, o1 = (float)ov[q].y;
      const float o2 = (float)ov[q].z, o3 = (float)ov[q].w;
      const float t0 = o0 * (yv[q].x - mb.x), t1 = o1 * (yv[q].y - mb.y);
      const float t2 = o2 * (yv[q].z - mb.z), t3 = o3 * (yv[q].w - mb.w);
      uint* base = tile_l + gp * 2304 + row * 18;
      *reinterpret_cast<uint2*>(base + c4 * 2) = make_uint2(pkh2(o0, o1), pkh2(o2, o3));
      *reinterpret_cast<uint2*>(base + 8 + c4 * 2) = make_uint2(pkh2(t0, t1), pkh2(t2, t3));
    }
    if (it + 1 < NCHUNK) ISSUE_LOADS(it + 1);  // in flight under compute
    __syncthreads();

    // Accumulate 8 channel-pairs from LDS.
    uint ofv[8], tvv[8];
    const uint* trow = tile_l + g * 2304 + r * 18;
    *reinterpret_cast<uint2*>(&ofv[0]) = *reinterpret_cast<const uint2*>(trow + 0);
    *reinterpret_cast<uint2*>(&ofv[2]) = *reinterpret_cast<const uint2*>(trow + 2);
    *reinterpret_cast<uint2*>(&ofv[4]) = *reinterpret_cast<const uint2*>(trow + 4);
    *reinterpret_cast<uint2*>(&ofv[6]) = *reinterpret_cast<const uint2*>(trow + 6);
    *reinterpret_cast<uint2*>(&tvv[0]) = *reinterpret_cast<const uint2*>(trow + 8);
    *reinterpret_cast<uint2*>(&tvv[2]) = *reinterpret_cast<const uint2*>(trow + 10);
    *reinterpret_cast<uint2*>(&tvv[4]) = *reinterpret_cast<const uint2*>(trow + 12);
    *reinterpret_cast<uint2*>(&tvv[6]) = *reinterpret_cast<const uint2*>(trow + 14);

#pragma unroll
    for (int p = 0; p < 8; ++p) {
      const uint4* rp =
          reinterpret_cast<const uint4*>(rec_l) + (size_t)(g * 96 + it * 8 + p) * 11;
      const uint A = ofv[p], T = tvv[p];
      uint4 R;
      R = rp[0];
      a[0] = dot2(A, R.x, a[0]); a[1] = dot2(A, R.y, a[1]);
      a[2] = dot2(A, R.z, a[2]); a[3] = dot2(A, R.w, a[3]);
      R = rp[1];
      a[4] = dot2(A, R.x, a[4]); a[5] = dot2(A, R.y, a[5]);
      a[6] = dot2(A, R.z, a[6]); a[7] = dot2(A, R.w, a[7]);
      R = rp[2];
      a[8] = dot2(A, R.x, a[8]); a[9] = dot2(A, R.y, a[9]);
      a[10] = dot2(A, R.z, a[10]); a[11] = dot2(A, R.w, a[11]);
      R = rp[3];
      a[12] = dot2(A, R.x, a[12]); a[13] = dot2(A, R.y, a[13]);
      a[14] = dot2(A, R.z, a[14]); a[15] = dot2(A, R.w, a[15]);
      R = rp[4];
      a[16] = dot2(A, R.x, a[16]); a[17] = dot2(A, R.y, a[17]);
      a[18] = dot2(A, R.z, a[18]); a[19] = dot2(A, R.w, a[19]);
      R = rp[5];
      a[20] = dot2(A, R.x, a[20]); a[21] = dot2(A, R.y, a[21]);
      a[22] = dot2(A, R.z, a[22]); a[23] = dot2(A, R.w, a[23]);
      R = rp[6];
      a[24] = dot2(A, R.x, a[24]); a[25] = dot2(A, R.y, a[25]);
      a[26] = dot2(A, R.z, a[26]); a[27] = dot2(A, R.w, a[27]);
      R = rp[7];
      a[28] = dot2(A, R.x, a[28]); a[29] = dot2(A, R.y, a[29]);
      a[30] = dot2(A, R.z, a[30]); a[31] = dot2(A, R.w, a[31]);
      R = rp[8];
      a[32] = dot2(A, R.x, a[32]); a[33] = dot2(A, R.y, a[33]);
      a[34] = dot2(A, R.z, a[34]); a[35] = dot2(A, R.w, a[35]);
      R = rp[9];
      pr[0] = dot2(T, R.x, pr[0]); pr[1] = dot2(T, R.y, pr[1]);
      pr[2] = dot2(T, R.z, pr[2]); pr[3] = dot2(T, R.w, pr[3]);
      R = rp[10];
      pr[4] = dot2(T, R.x, pr[4]); pr[5] = dot2(T, R.y, pr[5]);
      pr[6] = dot2(T, R.z, pr[6]); pr[7] = dot2(T, R.w, pr[7]);
    }
  }

  // ---- cross-group reduction (part overlays rec region) ----
  __syncthreads();  // all rec reads done before overwrite
  if (g == 1) {
#pragma unroll
    for (int k = 0; k < 36; ++k) part_l[k * 128 + r] = a[k];
#pragma unroll
    for (int j = 0; j < CC; ++j) part_l[(36 + j) * 128 + r] = pr[j];
  }
  __syncthreads();
  if (g == 1) return;
#pragma unroll
  for (int k = 0; k < 36; ++k) a[k] += part_l[k * 128 + r];
#pragma unroll
  for (int j = 0; j < CC; ++j) pr[j] += part_l[(36 + j) * 128 + r];

  const float vy = *vyp;

  // ---- Cholesky solve: M = vy*I + A ----
  float L[36];
#pragma unroll
  for (int j = 0; j < CC; ++j) {
    float s = a[TIDX(j, j)] + vy;
#pragma unroll
    for (int k = 0; k < CC; ++k) {
      if (k < j) s -= L[TIDX(j, k)] * L[TIDX(j, k)];
    }
    const float dj = sqrtf(s);
    L[TIDX(j, j)] = dj;
    const float invdj = 1.0f / dj;
#pragma unroll
    for (int i = j + 1; i < CC; ++i) {
      float tt = a[TIDX(i, j)];
#pragma unroll
      for (int k = 0; k < CC; ++k) {
        if (k < j) tt -= L[TIDX(i, k)] * L[TIDX(j, k)];
      }
      L[TIDX(i, j)] = tt * invdj;
    }
  }

  float invd[CC];
#pragma unroll
  for (int i = 0; i < CC; ++i) invd[i] = 1.0f / L[TIDX(i, i)];
  float Li[36];
#pragma unroll
  for (int j = 0; j < CC; ++j) {
    Li[TIDX(j, j)] = invd[j];
#pragma unroll
    for (int i = j + 1; i < CC; ++i) {
      float s = 0.f;
#pragma unroll
      for (int k = 0; k < CC; ++k) {
        if (k >= j && k < i) s += L[TIDX(i, k)] * Li[TIDX(k, j)];
      }
      Li[TIDX(i, j)] = -s * invd[i];
    }
  }

  float sig[36];
#pragma unroll
  for (int i = 0; i < CC; ++i) {
#pragma unroll
    for (int j = 0; j <= i; ++j) {
      float s = 0.f;
#pragma unroll
      for (int k = 0; k < CC; ++k) {
        if (k >= i) s += Li[TIDX(k, i)] * Li[TIDX(k, j)];
      }
      sig[TIDX(i, j)] = vy * s;
    }
  }

  float uvec[CC];
#pragma unroll
  for (int i = 0; i < CC; ++i) {
    float s = 0.f;
#pragma unroll
    for (int j = 0; j < CC; ++j) {
      if (j <= i) s += Li[TIDX(i, j)] * pr[j];
    }
    uvec[i] = s;
  }
  float xb[CC];
#pragma unroll
  for (int l = 0; l < CC; ++l) {
    float s = 0.f;
#pragma unroll
    for (int i = 0; i < CC; ++i) {
      if (i >= l) s += Li[TIDX(i, l)] * uvec[i];
    }
    xb[l] = s;
  }

  if (grow >= NN) return;

  float4* __restrict__ xo = reinterpret_cast<float4*>(out + (size_t)grow * CC);
  xo[0] = make_float4(xb[0], xb[1], xb[2], xb[3]);
  xo[1] = make_float4(xb[4], xb[5], xb[6], xb[7]);

  float4* __restrict__ so4 =
      reinterpret_cast<float4*>(out + (size_t)NN * CC + (size_t)grow * 64);
#pragma unroll
  for (int i = 0; i < CC; ++i) {
    float rowv[CC];
#pragma unroll
    for (int j = 0; j < CC; ++j) {
      rowv[j] = (j <= i) ? sig[TIDX(i, j)] : sig[TIDX(j, i)];
    }
    so4[i * 2 + 0] = make_float4(rowv[0], rowv[1], rowv[2], rowv[3]);
    so4[i * 2 + 1] = make_float4(rowv[4], rowv[5], rowv[6], rowv[7]);
  }
}

extern "C" void kernel_launch(void* const* d_in, const int* in_sizes, int n_in,
                              void* d_out, int out_size, void* d_ws, size_t ws_size,
                              hipStream_t stream) {
  const float* Y = (const float*)d_in[0];
  const int* O = (const int*)d_in[1];
  const float* mbar = (const float*)d_in[2];
  const float* wbar = (const float*)d_in[3];
  const float* Sigmaw = (const float*)d_in[4];
  const float* vyp = (const float*)d_in[5];
  float* out = (float*)d_out;
  uint* recpk = (uint*)d_ws;  // 192*44*4 = 33792 bytes

  vbpca_prep<<<3, 64, 0, stream>>>(wbar, Sigmaw, recpk);
  vbpca_main<<<(NN + ROWS - 1) / ROWS, 256, 0, stream>>>(Y, O, recpk, mbar, vyp, out);
}